// Round 1
// baseline (262.719 us; speedup 1.0000x reference)
//
#include <hip/hip_runtime.h>
#include <stdint.h>

typedef __attribute__((ext_vector_type(8))) short short8;
typedef __attribute__((ext_vector_type(4))) float f32x4;
typedef __attribute__((ext_vector_type(4))) float f4;
typedef __attribute__((ext_vector_type(4))) ushort us4;

#define AS1 __attribute__((address_space(1)))
#define AS3 __attribute__((address_space(3)))

__device__ __forceinline__ ushort f2bf(float f) {
  uint u = __builtin_bit_cast(uint, f);
  u += 0x7fffu + ((u >> 16) & 1u);
  return (ushort)(u >> 16);
}

// ---------------- f32 -> bf16 conversion ----------------
__global__ void cvt_bf16(const float* __restrict__ in, ushort* __restrict__ out, int n4) {
  int i = blockIdx.x * blockDim.x + threadIdx.x;
  int stride = gridDim.x * blockDim.x;
  for (; i < n4; i += stride) {
    f4 v = ((const f4*)in)[i];
    us4 o;
    o[0] = f2bf(v[0]); o[1] = f2bf(v[1]); o[2] = f2bf(v[2]); o[3] = f2bf(v[3]);
    ((us4*)out)[i] = o;
  }
}

// ---------------- GEMM: C[M,N] = A[M,K] * B[N,K]^T + bias ----------------
// 128x128 tile, BK=64, 4 waves (2x2), 16x16x32 bf16 MFMA.
// LDS tiles [128 rows][64 k elems] = 128B rows, XOR-swizzled:
//   physical_byte = logical_byte ^ ((row & 7) << 4)   (row-preserving involution)

__device__ __forceinline__ void stage_tile(const ushort* __restrict__ gbase, int row0,
                                           int pitch, int k0, char* lds, int tid) {
#pragma unroll
  for (int i = 0; i < 4; ++i) {
    uint chunk = i * 256 + tid;                 // physical 16B chunk index
    uint Q = chunk << 4;                        // physical byte
    uint L = Q ^ (((Q >> 7) & 7u) << 4);        // logical byte (involution)
    uint row = L >> 7;
    uint kb = L & 127u;
    const char* g = (const char*)(gbase + (size_t)(row0 + (int)row) * pitch + k0) + kb;
    char* l = lds + (size_t)((i * 256 + (tid & ~63)) << 4);  // wave-uniform base
    __builtin_amdgcn_global_load_lds((const AS1 void*)g, (AS3 void*)l, 16, 0, 0);
  }
}

template <int OUT_F32>
__global__ __launch_bounds__(256) void gemm_bt(const ushort* __restrict__ A,
                                               const ushort* __restrict__ Bw,
                                               const float* __restrict__ bias,
                                               void* __restrict__ Cout,
                                               int M, int N, int K) {
  __shared__ char sA[16384];
  __shared__ char sB[16384];
  int tid = threadIdx.x;
  int nbn = N >> 7;
  int bm = blockIdx.x / nbn, bn = blockIdx.x % nbn;
  int lane = tid & 63, l15 = lane & 15, lk = lane >> 4;
  int w = tid >> 6;
  int wr = w >> 1, wc = w & 1;

  f32x4 acc[4][4];
  f32x4 zero = {0.f, 0.f, 0.f, 0.f};
#pragma unroll
  for (int i = 0; i < 4; ++i)
#pragma unroll
    for (int j = 0; j < 4; ++j) acc[i][j] = zero;

  for (int k0 = 0; k0 < K; k0 += 64) {
    stage_tile(A, bm * 128, K, k0, sA, tid);
    stage_tile(Bw, bn * 128, K, k0, sB, tid);
    __syncthreads();

    short8 af[4][2], bf[4][2];
#pragma unroll
    for (int mt = 0; mt < 4; ++mt)
#pragma unroll
      for (int kk = 0; kk < 2; ++kk) {
        uint rowa = wr * 64 + mt * 16 + l15;
        uint ba = (rowa << 7) + (kk << 6) + (lk << 4);
        af[mt][kk] = *(const short8*)&sA[ba ^ ((rowa & 7u) << 4)];
        uint rowb = wc * 64 + mt * 16 + l15;
        uint bb = (rowb << 7) + (kk << 6) + (lk << 4);
        bf[mt][kk] = *(const short8*)&sB[bb ^ ((rowb & 7u) << 4)];
      }
#pragma unroll
    for (int kk = 0; kk < 2; ++kk)
#pragma unroll
      for (int mt = 0; mt < 4; ++mt)
#pragma unroll
        for (int nt = 0; nt < 4; ++nt)
          acc[mt][nt] = __builtin_amdgcn_mfma_f32_16x16x32_bf16(af[mt][kk], bf[nt][kk],
                                                                acc[mt][nt], 0, 0, 0);
    __syncthreads();
  }

#pragma unroll
  for (int mt = 0; mt < 4; ++mt)
#pragma unroll
    for (int nt = 0; nt < 4; ++nt)
#pragma unroll
      for (int r = 0; r < 4; ++r) {
        int row = bm * 128 + wr * 64 + mt * 16 + lk * 4 + r;
        int col = bn * 128 + wc * 64 + nt * 16 + l15;
        float v = acc[mt][nt][r] + bias[col];
        if constexpr (OUT_F32)
          ((float*)Cout)[(size_t)row * N + col] = v;
        else
          ((ushort*)Cout)[(size_t)row * N + col] = f2bf(v);
      }
}

// ---------------- cron-root block-sparse attention ----------------
// qkv: [B*S][3072] bf16, cols: q = h*64+d, k = 1024 + h*64+d, v = 2048 + h*64+d
// grid = B*H*nb = 4096 blocks of 256 threads; each wave = 16 query rows.
__global__ __launch_bounds__(256) void cron_attn(const ushort* __restrict__ qkv,
                                                 ushort* __restrict__ aout) {
  const int S = 4096, CQ = 3072;
  int bid = blockIdx.x;
  int n = bid & 63;
  int h = (bid >> 6) & 15;
  int b = bid >> 10;
  int tid = threadIdx.x;
  int w = tid >> 6, lane = tid & 63, l15 = lane & 15, lk = lane >> 4;

  const ushort* qp = qkv + (size_t)b * S * CQ + h * 64;
  const ushort* kp = qp + 1024;
  const ushort* vp = qp + 2048;

  __shared__ char vT[16384];    // [64 d][128 key] bf16, swizzled 256B rows
  __shared__ char pL[4][4096];  // per-wave [16 q][128 key] bf16, swizzled

  // ---- stage V^T (concat local block + 64 summary slots) ----
  {
    int r = tid >> 1;     // concat key index 0..127
    int half = tid & 1;   // d half: half*32 .. +31
    int srow = (r < 64) ? (n * 64 + r) : ((r - 64) * 64 + 63);
    const ushort* src = vp + (size_t)srow * CQ + half * 32;
    short8 vv0 = ((const short8*)src)[0];
    short8 vv1 = ((const short8*)src)[1];
    short8 vv2 = ((const short8*)src)[2];
    short8 vv3 = ((const short8*)src)[3];
#pragma unroll
    for (int j = 0; j < 8; ++j) {
      int d0 = half * 32 + j;
      *(short*)&vT[(uint)(d0 * 256 + r * 2) ^ (((uint)d0 & 7u) << 4)] = vv0[j];
      int d1 = half * 32 + 8 + j;
      *(short*)&vT[(uint)(d1 * 256 + r * 2) ^ (((uint)d1 & 7u) << 4)] = vv1[j];
      int d2 = half * 32 + 16 + j;
      *(short*)&vT[(uint)(d2 * 256 + r * 2) ^ (((uint)d2 & 7u) << 4)] = vv2[j];
      int d3 = half * 32 + 24 + j;
      *(short*)&vT[(uint)(d3 * 256 + r * 2) ^ (((uint)d3 & 7u) << 4)] = vv3[j];
    }
  }
  __syncthreads();

  // ---- Q fragments (A operand): row = l15, k contiguous ----
  short8 aq[2];
  {
    int srow = n * 64 + w * 16 + l15;
#pragma unroll
    for (int kk = 0; kk < 2; ++kk)
      aq[kk] = *(const short8*)(qp + (size_t)srow * CQ + kk * 32 + lk * 8);
  }

  // ---- scores: 8 col-tiles (4 local, 4 summary) ----
  f32x4 sc[8];
  f32x4 zero = {0.f, 0.f, 0.f, 0.f};
#pragma unroll
  for (int c = 0; c < 8; ++c) sc[c] = zero;
#pragma unroll
  for (int c = 0; c < 8; ++c) {
    int key = (c < 4) ? (n * 64 + c * 16 + l15) : (((c - 4) * 16 + l15) * 64 + 63);
    const ushort* kr = kp + (size_t)key * CQ;
#pragma unroll
    for (int kk = 0; kk < 2; ++kk) {
      short8 bk = *(const short8*)(kr + kk * 32 + lk * 8);
      sc[c] = __builtin_amdgcn_mfma_f32_16x16x32_bf16(aq[kk], bk, sc[c], 0, 0, 0);
    }
  }

  // ---- mask + scale ----
  float p[8][4];
  int qrow = w * 16 + lk * 4;
#pragma unroll
  for (int c = 0; c < 8; ++c)
#pragma unroll
    for (int r = 0; r < 4; ++r) {
      float s = sc[c][r] * 0.125f;
      bool ok = (c < 4) ? ((qrow + r) >= (c * 16 + l15)) : (((c - 4) * 16 + l15) < n);
      p[c][r] = ok ? s : -1e30f;
    }

  // ---- row softmax (row lives in 16 lanes x 8 in-lane values) ----
#pragma unroll
  for (int r = 0; r < 4; ++r) {
    float m = p[0][r];
#pragma unroll
    for (int c = 1; c < 8; ++c) m = fmaxf(m, p[c][r]);
    m = fmaxf(m, __shfl_xor(m, 1));
    m = fmaxf(m, __shfl_xor(m, 2));
    m = fmaxf(m, __shfl_xor(m, 4));
    m = fmaxf(m, __shfl_xor(m, 8));
    float sum = 0.f;
#pragma unroll
    for (int c = 0; c < 8; ++c) {
      p[c][r] = __expf(p[c][r] - m);
      sum += p[c][r];
    }
    sum += __shfl_xor(sum, 1);
    sum += __shfl_xor(sum, 2);
    sum += __shfl_xor(sum, 4);
    sum += __shfl_xor(sum, 8);
    float rs = 1.f / sum;
#pragma unroll
    for (int c = 0; c < 8; ++c) p[c][r] *= rs;
  }

  // ---- P -> LDS (D layout) then re-read as A fragments ----
  char* myP = pL[w];
#pragma unroll
  for (int c = 0; c < 8; ++c)
#pragma unroll
    for (int r = 0; r < 4; ++r) {
      uint row = lk * 4 + r;
      uint byte = row * 256 + (c * 16 + l15) * 2;
      *(short*)&myP[byte ^ ((row & 7u) << 4)] = (short)f2bf(p[c][r]);
    }
  short8 ap[4];
#pragma unroll
  for (int kk = 0; kk < 4; ++kk) {
    uint row = (uint)l15;
    uint byte = row * 256 + (kk * 32 + lk * 8) * 2;
    ap[kk] = *(const short8*)&myP[byte ^ ((row & 7u) << 4)];
  }

  // ---- PV: out[16 x 64] ----
  f32x4 ao[4];
#pragma unroll
  for (int dc = 0; dc < 4; ++dc) ao[dc] = zero;
#pragma unroll
  for (int dc = 0; dc < 4; ++dc)
#pragma unroll
    for (int kk = 0; kk < 4; ++kk) {
      uint d = dc * 16 + l15;
      uint byte = d * 256 + (kk * 32 + lk * 8) * 2;
      short8 bv = *(const short8*)&vT[byte ^ ((d & 7u) << 4)];
      ao[dc] = __builtin_amdgcn_mfma_f32_16x16x32_bf16(ap[kk], bv, ao[dc], 0, 0, 0);
    }

  // ---- write attn out [B*S][1024], col = h*64 + d ----
#pragma unroll
  for (int dc = 0; dc < 4; ++dc)
#pragma unroll
    for (int r = 0; r < 4; ++r) {
      int srow = n * 64 + w * 16 + lk * 4 + r;
      int col = h * 64 + dc * 16 + l15;
      aout[((size_t)(b * S + srow)) * 1024 + col] = f2bf(ao[dc][r]);
    }
}

// ---------------- launch ----------------
extern "C" void kernel_launch(void* const* d_in, const int* in_sizes, int n_in,
                              void* d_out, int out_size, void* d_ws, size_t ws_size,
                              hipStream_t stream) {
  const float* x = (const float*)d_in[0];
  const float* wi = (const float*)d_in[1];
  const float* bi = (const float*)d_in[2];
  const float* wo = (const float*)d_in[3];
  const float* bo = (const float*)d_in[4];
  float* out = (float*)d_out;
  char* ws = (char*)d_ws;

  ushort* xb = (ushort*)(ws);                           // 16384*1024*2 = 32MB
  ushort* wib = (ushort*)(ws + (size_t)33554432);       // 3072*1024*2  = 6MB
  ushort* wob = (ushort*)(ws + (size_t)39845888);       // 1024*1024*2  = 2MB
  ushort* qkvb = (ushort*)(ws + (size_t)41943040);      // 16384*3072*2 = 96MB
  ushort* aob = (ushort*)(ws + (size_t)142606336);      // 16384*1024*2 = 32MB

  cvt_bf16<<<2048, 256, 0, stream>>>(x, xb, (16384 * 1024) / 4);
  cvt_bf16<<<768, 256, 0, stream>>>(wi, wib, (3072 * 1024) / 4);
  cvt_bf16<<<256, 256, 0, stream>>>(wo, wob, (1024 * 1024) / 4);

  gemm_bt<0><<<128 * 24, 256, 0, stream>>>(xb, wib, bi, qkvb, 16384, 3072, 1024);
  cron_attn<<<4096, 256, 0, stream>>>(qkvb, aob);
  gemm_bt<1><<<128 * 8, 256, 0, stream>>>(aob, wob, bo, out, 16384, 1024, 1024);
}

// Round 2
// 225.064 us; speedup vs baseline: 1.1673x; 1.1673x over previous
//
#include <hip/hip_runtime.h>
#include <stdint.h>

typedef __attribute__((ext_vector_type(8))) short short8;
typedef __attribute__((ext_vector_type(4))) float f32x4;
typedef __attribute__((ext_vector_type(4))) float f4;
typedef __attribute__((ext_vector_type(4))) ushort us4;

#define AS1 __attribute__((address_space(1)))
#define AS3 __attribute__((address_space(3)))

__device__ __forceinline__ ushort f2bf(float f) {
  uint u = __builtin_bit_cast(uint, f);
  u += 0x7fffu + ((u >> 16) & 1u);
  return (ushort)(u >> 16);
}

// ---------------- f32 -> bf16 conversion ----------------
__global__ void cvt_bf16(const float* __restrict__ in, ushort* __restrict__ out, int n4) {
  int i = blockIdx.x * blockDim.x + threadIdx.x;
  int stride = gridDim.x * blockDim.x;
  for (; i < n4; i += stride) {
    f4 v = ((const f4*)in)[i];
    us4 o;
    o[0] = f2bf(v[0]); o[1] = f2bf(v[1]); o[2] = f2bf(v[2]); o[3] = f2bf(v[3]);
    ((us4*)out)[i] = o;
  }
}

// ---------------- 256x256-tile 8-phase GEMM: C[M,N] = A[M,K]*B[N,K]^T + bias ----
// 8 waves (2M x 4N), BK=64, double-buffered LDS [2][256][64] bf16 per matrix.
// Row-XOR swizzle: physical_byte = logical_byte ^ ((row & 7) << 4).
// Half-tile order per K-tile: (B-h0, B-h1, A-h0, A-h1); stage lookahead = 7
// half-tiles; steady-state 3 half-tiles (vmcnt 6) in flight.

__device__ __forceinline__ void stage_half(const ushort* __restrict__ g, int pitch,
                                           int row0, int k0, char* ldsbase, int tid) {
#pragma unroll
  for (int i = 0; i < 2; ++i) {
    uint chunk = i * 512 + tid;              // physical 16B chunk in 16KB half-tile
    uint Q = chunk << 4;
    uint L = Q ^ (((Q >> 7) & 7u) << 4);     // logical byte (involution, row-preserving)
    uint row = L >> 7;                       // 0..127
    uint kb = L & 127u;
    const char* gp = (const char*)(g + (size_t)(row0 + (int)row) * pitch + k0) + kb;
    char* lp = ldsbase + ((i * 512 + (tid & ~63)) << 4);  // wave-uniform base
    __builtin_amdgcn_global_load_lds((const AS1 void*)gp, (AS3 void*)lp, 16, 0, 0);
  }
}

__device__ __forceinline__ void stage_j(int j, const ushort* __restrict__ A,
                                        const ushort* __restrict__ Bw, int K,
                                        int arow0, int brow0, char* sA, char* sB, int tid) {
  int t = j >> 2, h = j & 3;
  int k0 = t << 6;
  char* base = ((h < 2) ? sB : sA) + ((t & 1) << 15) + ((h & 1) << 14);
  const ushort* g = (h < 2) ? Bw : A;
  int row0 = ((h < 2) ? brow0 : arow0) + ((h & 1) << 7);
  stage_half(g, K, row0, k0, base, tid);
}

template <int OUT_F32>
__global__ __launch_bounds__(512, 1) void gemm256(const ushort* __restrict__ A,
                                                  const ushort* __restrict__ Bw,
                                                  const float* __restrict__ bias,
                                                  void* __restrict__ Cout,
                                                  int M, int N, int K, int gn) {
  __shared__ char sA[65536];
  __shared__ char sB[65536];
  const int tid = threadIdx.x;
  const int lane = tid & 63, l15 = lane & 15, lk = lane >> 4;
  const int w = tid >> 6;
  const int wm = w >> 2, wn = w & 3;
  const int NT = K >> 6;

  // XCD-aware swizzle (gridDim.x % 8 == 0 for all our grids)
  int q8 = gridDim.x >> 3;
  int bid = blockIdx.x;
  int swz = (bid & 7) * q8 + (bid >> 3);
  int bm = swz / gn, bn = swz % gn;
  const int arow0 = bm << 8, brow0 = bn << 8;

  f32x4 acc[8][4];
  f32x4 zero = {0.f, 0.f, 0.f, 0.f};
#pragma unroll
  for (int i = 0; i < 8; ++i)
#pragma unroll
    for (int j = 0; j < 4; ++j) acc[i][j] = zero;

  // prologue: stage half-tiles 0..6 (K-tile 0 complete + 3 of K-tile 1)
#pragma unroll
  for (int j = 0; j < 7; ++j)
    if (j < 4 * NT) stage_j(j, A, Bw, K, arow0, brow0, sA, sB, tid);
  asm volatile("s_waitcnt vmcnt(6)" ::: "memory");
  __builtin_amdgcn_s_barrier();

  for (int t = 0; t < NT; ++t) {
    const char* bA = sA + ((t & 1) << 15);
    const char* bB = sB + ((t & 1) << 15);
    short8 bfr[4][2];
#pragma unroll
    for (int qd = 0; qd < 4; ++qd) {
      short8 afr[2][2];
      if (qd == 0) {
#pragma unroll
        for (int ni = 0; ni < 4; ++ni)
#pragma unroll
          for (int kk = 0; kk < 2; ++kk) {
            uint row = (uint)(wn * 64 + ni * 16 + l15);
            uint byte = (row << 7) + (kk << 6) + (lk << 4);
            bfr[ni][kk] = *(const short8*)&bB[byte ^ ((row & 7u) << 4)];
          }
      }
#pragma unroll
      for (int mi = 0; mi < 2; ++mi)
#pragma unroll
        for (int kk = 0; kk < 2; ++kk) {
          uint row = (uint)(wm * 128 + (qd * 2 + mi) * 16 + l15);
          uint byte = (row << 7) + (kk << 6) + (lk << 4);
          afr[mi][kk] = *(const short8*)&bA[byte ^ ((row & 7u) << 4)];
        }
      int j = 4 * t + qd + 7;
      if (j < 4 * NT) stage_j(j, A, Bw, K, arow0, brow0, sA, sB, tid);
      if (qd == 3) {
        if (t < NT - 2) asm volatile("s_waitcnt vmcnt(6)" ::: "memory");
        else if (t == NT - 2) asm volatile("s_waitcnt vmcnt(0)" ::: "memory");
      }
      __builtin_amdgcn_s_barrier();
      asm volatile("s_waitcnt lgkmcnt(0)" ::: "memory");
      __builtin_amdgcn_s_setprio(1);
#pragma unroll
      for (int kk = 0; kk < 2; ++kk)
#pragma unroll
        for (int mi = 0; mi < 2; ++mi)
#pragma unroll
          for (int ni = 0; ni < 4; ++ni)
            acc[qd * 2 + mi][ni] = __builtin_amdgcn_mfma_f32_16x16x32_bf16(
                afr[mi][kk], bfr[ni][kk], acc[qd * 2 + mi][ni], 0, 0, 0);
      __builtin_amdgcn_s_setprio(0);
      __builtin_amdgcn_s_barrier();
    }
  }

  // epilogue: C-write (C/D layout: col=lane&15, row=(lane>>4)*4+reg)
#pragma unroll
  for (int m = 0; m < 8; ++m)
#pragma unroll
    for (int ni = 0; ni < 4; ++ni)
#pragma unroll
      for (int r = 0; r < 4; ++r) {
        int row = arow0 + wm * 128 + m * 16 + lk * 4 + r;
        int col = brow0 + wn * 64 + ni * 16 + l15;
        float v = acc[m][ni][r] + bias[col];
        if constexpr (OUT_F32)
          ((float*)Cout)[(size_t)row * N + col] = v;
        else
          ((ushort*)Cout)[(size_t)row * N + col] = f2bf(v);
      }
}

// ---------------- cron-root block-sparse attention ----------------
// qkv: [B*S][3072] bf16, cols: q = h*64+d, k = 1024 + h*64+d, v = 2048 + h*64+d
// grid = B*H*nb = 4096 blocks of 256 threads; each wave = 16 query rows.
__global__ __launch_bounds__(256) void cron_attn(const ushort* __restrict__ qkv,
                                                 ushort* __restrict__ aout) {
  const int S = 4096, CQ = 3072;
  int bid = blockIdx.x;
  int n = bid & 63;
  int h = (bid >> 6) & 15;
  int b = bid >> 10;
  int tid = threadIdx.x;
  int w = tid >> 6, lane = tid & 63, l15 = lane & 15, lk = lane >> 4;

  const ushort* qp = qkv + (size_t)b * S * CQ + h * 64;
  const ushort* kp = qp + 1024;
  const ushort* vp = qp + 2048;

  __shared__ char vT[16384];    // [64 d][128 key] bf16, swizzled 256B rows
  __shared__ char pL[4][4096];  // per-wave [16 q][128 key] bf16, swizzled

  // ---- stage V^T (concat local block + 64 summary slots) ----
  {
    int r = tid >> 1;     // concat key index 0..127
    int half = tid & 1;   // d half: half*32 .. +31
    int srow = (r < 64) ? (n * 64 + r) : ((r - 64) * 64 + 63);
    const ushort* src = vp + (size_t)srow * CQ + half * 32;
    short8 vv0 = ((const short8*)src)[0];
    short8 vv1 = ((const short8*)src)[1];
    short8 vv2 = ((const short8*)src)[2];
    short8 vv3 = ((const short8*)src)[3];
#pragma unroll
    for (int j = 0; j < 8; ++j) {
      int d0 = half * 32 + j;
      *(short*)&vT[(uint)(d0 * 256 + r * 2) ^ (((uint)d0 & 7u) << 4)] = vv0[j];
      int d1 = half * 32 + 8 + j;
      *(short*)&vT[(uint)(d1 * 256 + r * 2) ^ (((uint)d1 & 7u) << 4)] = vv1[j];
      int d2 = half * 32 + 16 + j;
      *(short*)&vT[(uint)(d2 * 256 + r * 2) ^ (((uint)d2 & 7u) << 4)] = vv2[j];
      int d3 = half * 32 + 24 + j;
      *(short*)&vT[(uint)(d3 * 256 + r * 2) ^ (((uint)d3 & 7u) << 4)] = vv3[j];
    }
  }
  __syncthreads();

  // ---- Q fragments (A operand): row = l15, k contiguous ----
  short8 aq[2];
  {
    int srow = n * 64 + w * 16 + l15;
#pragma unroll
    for (int kk = 0; kk < 2; ++kk)
      aq[kk] = *(const short8*)(qp + (size_t)srow * CQ + kk * 32 + lk * 8);
  }

  // ---- scores: 8 col-tiles (4 local, 4 summary) ----
  f32x4 sc[8];
  f32x4 zero = {0.f, 0.f, 0.f, 0.f};
#pragma unroll
  for (int c = 0; c < 8; ++c) sc[c] = zero;
#pragma unroll
  for (int c = 0; c < 8; ++c) {
    int key = (c < 4) ? (n * 64 + c * 16 + l15) : (((c - 4) * 16 + l15) * 64 + 63);
    const ushort* kr = kp + (size_t)key * CQ;
#pragma unroll
    for (int kk = 0; kk < 2; ++kk) {
      short8 bk = *(const short8*)(kr + kk * 32 + lk * 8);
      sc[c] = __builtin_amdgcn_mfma_f32_16x16x32_bf16(aq[kk], bk, sc[c], 0, 0, 0);
    }
  }

  // ---- mask + scale ----
  float p[8][4];
  int qrow = w * 16 + lk * 4;
#pragma unroll
  for (int c = 0; c < 8; ++c)
#pragma unroll
    for (int r = 0; r < 4; ++r) {
      float s = sc[c][r] * 0.125f;
      bool ok = (c < 4) ? ((qrow + r) >= (c * 16 + l15)) : (((c - 4) * 16 + l15) < n);
      p[c][r] = ok ? s : -1e30f;
    }

  // ---- row softmax (row lives in 16 lanes x 8 in-lane values) ----
#pragma unroll
  for (int r = 0; r < 4; ++r) {
    float m = p[0][r];
#pragma unroll
    for (int c = 1; c < 8; ++c) m = fmaxf(m, p[c][r]);
    m = fmaxf(m, __shfl_xor(m, 1));
    m = fmaxf(m, __shfl_xor(m, 2));
    m = fmaxf(m, __shfl_xor(m, 4));
    m = fmaxf(m, __shfl_xor(m, 8));
    float sum = 0.f;
#pragma unroll
    for (int c = 0; c < 8; ++c) {
      p[c][r] = __expf(p[c][r] - m);
      sum += p[c][r];
    }
    sum += __shfl_xor(sum, 1);
    sum += __shfl_xor(sum, 2);
    sum += __shfl_xor(sum, 4);
    sum += __shfl_xor(sum, 8);
    float rs = 1.f / sum;
#pragma unroll
    for (int c = 0; c < 8; ++c) p[c][r] *= rs;
  }

  // ---- P -> LDS (D layout) then re-read as A fragments ----
  char* myP = pL[w];
#pragma unroll
  for (int c = 0; c < 8; ++c)
#pragma unroll
    for (int r = 0; r < 4; ++r) {
      uint row = lk * 4 + r;
      uint byte = row * 256 + (c * 16 + l15) * 2;
      *(short*)&myP[byte ^ ((row & 7u) << 4)] = (short)f2bf(p[c][r]);
    }
  short8 ap[4];
#pragma unroll
  for (int kk = 0; kk < 4; ++kk) {
    uint row = (uint)l15;
    uint byte = row * 256 + (kk * 32 + lk * 8) * 2;
    ap[kk] = *(const short8*)&myP[byte ^ ((row & 7u) << 4)];
  }

  // ---- PV: out[16 x 64] ----
  f32x4 ao[4];
#pragma unroll
  for (int dc = 0; dc < 4; ++dc) ao[dc] = zero;
#pragma unroll
  for (int dc = 0; dc < 4; ++dc)
#pragma unroll
    for (int kk = 0; kk < 4; ++kk) {
      uint d = dc * 16 + l15;
      uint byte = d * 256 + (kk * 32 + lk * 8) * 2;
      short8 bv = *(const short8*)&vT[byte ^ ((d & 7u) << 4)];
      ao[dc] = __builtin_amdgcn_mfma_f32_16x16x32_bf16(ap[kk], bv, ao[dc], 0, 0, 0);
    }

  // ---- write attn out [B*S][1024], col = h*64 + d ----
#pragma unroll
  for (int dc = 0; dc < 4; ++dc)
#pragma unroll
    for (int r = 0; r < 4; ++r) {
      int srow = n * 64 + w * 16 + lk * 4 + r;
      int col = h * 64 + dc * 16 + l15;
      aout[((size_t)(b * S + srow)) * 1024 + col] = f2bf(ao[dc][r]);
    }
}

// ---------------- launch ----------------
extern "C" void kernel_launch(void* const* d_in, const int* in_sizes, int n_in,
                              void* d_out, int out_size, void* d_ws, size_t ws_size,
                              hipStream_t stream) {
  const float* x = (const float*)d_in[0];
  const float* wi = (const float*)d_in[1];
  const float* bi = (const float*)d_in[2];
  const float* wo = (const float*)d_in[3];
  const float* bo = (const float*)d_in[4];
  float* out = (float*)d_out;
  char* ws = (char*)d_ws;

  ushort* xb = (ushort*)(ws);                           // 16384*1024*2 = 32MB
  ushort* wib = (ushort*)(ws + (size_t)33554432);       // 3072*1024*2  = 6MB
  ushort* wob = (ushort*)(ws + (size_t)39845888);       // 1024*1024*2  = 2MB
  ushort* qkvb = (ushort*)(ws + (size_t)41943040);      // 16384*3072*2 = 96MB
  ushort* aob = (ushort*)(ws + (size_t)142606336);      // 16384*1024*2 = 32MB

  cvt_bf16<<<2048, 256, 0, stream>>>(x, xb, (16384 * 1024) / 4);
  cvt_bf16<<<768, 256, 0, stream>>>(wi, wib, (3072 * 1024) / 4);
  cvt_bf16<<<256, 256, 0, stream>>>(wo, wob, (1024 * 1024) / 4);

  gemm256<0><<<64 * 12, 512, 0, stream>>>(xb, wib, bi, qkvb, 16384, 3072, 1024, 12);
  cron_attn<<<4096, 256, 0, stream>>>(qkvb, aob);
  gemm256<1><<<64 * 4, 512, 0, stream>>>(aob, wob, bo, out, 16384, 1024, 1024, 4);
}